// Round 2
// baseline (5408.675 us; speedup 1.0000x reference)
//
#include <hip/hip_runtime.h>
#include <hip/hip_bf16.h>

// out[i][d] = bias[d]  (float4 vectorized)
__global__ __launch_bounds__(256) void init_out_kernel(float* __restrict__ out,
                                                       const float* __restrict__ bias,
                                                       long long total4) {
    long long i = (long long)blockIdx.x * blockDim.x + threadIdx.x;
    if (i >= total4) return;
    float4 b = ((const float4*)bias)[(int)(i & 31)];
    ((float4*)out)[i] = b;
}

// support[N,128] = A[N,128] @ W[128,128], fp32 vector ALU, 128-row tiles,
// 8x8 register blocking per thread, W/A K-chunks staged in LDS.
__global__ __launch_bounds__(256) void gemm_kernel(const float* __restrict__ A,
                                                   const float* __restrict__ W,
                                                   float* __restrict__ S,
                                                   int N) {
    __shared__ float sIn[128][33];   // +1 pad: conflict-free column reads
    __shared__ float sW[32][128];

    const int tid = threadIdx.x;
    const int tx = tid & 15;    // col group: cols {tx*4..+3} and {64+tx*4..+3}
    const int ty = tid >> 4;    // row group: rows ty*8..ty*8+7
    const int row0 = blockIdx.x * 128;

    float acc[8][8];
#pragma unroll
    for (int i = 0; i < 8; ++i)
#pragma unroll
        for (int j = 0; j < 8; ++j) acc[i][j] = 0.f;

    for (int kc = 0; kc < 128; kc += 32) {
        // stage A tile: 128 rows x 32 k  (8 threads/row, float4 each, 4 passes)
#pragma unroll
        for (int p = 0; p < 4; ++p) {
            int r = p * 32 + (tid >> 3);
            int q = tid & 7;
            int grow = row0 + r;
            float4 v = make_float4(0.f, 0.f, 0.f, 0.f);
            if (grow < N) v = *(const float4*)&A[(size_t)grow * 128 + kc + q * 4];
            sIn[r][q * 4 + 0] = v.x;
            sIn[r][q * 4 + 1] = v.y;
            sIn[r][q * 4 + 2] = v.z;
            sIn[r][q * 4 + 3] = v.w;
        }
        // stage W tile: 32 k x 128 cols
#pragma unroll
        for (int p = 0; p < 4; ++p) {
            int kr = p * 8 + (tid >> 5);
            int c4 = tid & 31;
            float4 v = *(const float4*)&W[(size_t)(kc + kr) * 128 + c4 * 4];
            *(float4*)&sW[kr][c4 * 4] = v;
        }
        __syncthreads();

#pragma unroll
        for (int k = 0; k < 32; ++k) {
            float a[8];
#pragma unroll
            for (int i = 0; i < 8; ++i) a[i] = sIn[ty * 8 + i][k];
            float4 w0 = *(float4*)&sW[k][tx * 4];
            float4 w1 = *(float4*)&sW[k][64 + tx * 4];
#pragma unroll
            for (int i = 0; i < 8; ++i) {
                acc[i][0] += a[i] * w0.x;
                acc[i][1] += a[i] * w0.y;
                acc[i][2] += a[i] * w0.z;
                acc[i][3] += a[i] * w0.w;
                acc[i][4] += a[i] * w1.x;
                acc[i][5] += a[i] * w1.y;
                acc[i][6] += a[i] * w1.z;
                acc[i][7] += a[i] * w1.w;
            }
        }
        __syncthreads();
    }

#pragma unroll
    for (int i = 0; i < 8; ++i) {
        int grow = row0 + ty * 8 + i;
        if (grow < N) {
            float4 v0 = make_float4(acc[i][0], acc[i][1], acc[i][2], acc[i][3]);
            float4 v1 = make_float4(acc[i][4], acc[i][5], acc[i][6], acc[i][7]);
            *(float4*)&S[(size_t)grow * 128 + tx * 4] = v0;
            *(float4*)&S[(size_t)grow * 128 + 64 + tx * 4] = v1;
        }
    }
}

// 2E directed messages; 32 threads per message, each thread: float4 gather from
// support[src], scale by alpha, 4 fp32 atomicAdds into out[dst].
// NOTE: harness delivers integer inputs as int32 (not int64) — cast accordingly.
__global__ __launch_bounds__(256) void scatter_kernel(const float* __restrict__ support,
                                                      const int* __restrict__ ei,
                                                      const int* __restrict__ rel,
                                                      const float* __restrict__ alpha,
                                                      float* __restrict__ out,
                                                      int E) {
    long long tid = (long long)blockIdx.x * blockDim.x + threadIdx.x;
    long long mid = tid >> 5;                 // message id
    if (mid >= 2LL * E) return;
    int lane4 = (int)(tid & 31);

    bool fwd = mid < E;
    int e = (int)(fwd ? mid : (mid - E));
    int r = ei[e];
    int c = ei[e + E];
    int src = fwd ? c : r;
    int dst = fwd ? r : c;
    int rr = rel[e];
    float alp = (rr == 0) ? 0.f : alpha[rr];   // padding_idx=0 -> zero weight
    if (alp == 0.f) return;

    const float4 v = *(const float4*)&support[(size_t)src * 128 + lane4 * 4];
    float* o = &out[(size_t)dst * 128 + lane4 * 4];
    atomicAdd(o + 0, alp * v.x);
    atomicAdd(o + 1, alp * v.y);
    atomicAdd(o + 2, alp * v.z);
    atomicAdd(o + 3, alp * v.w);
}

extern "C" void kernel_launch(void* const* d_in, const int* in_sizes, int n_in,
                              void* d_out, int out_size, void* d_ws, size_t ws_size,
                              hipStream_t stream) {
    const float* input  = (const float*)d_in[0];
    const int*   ei     = (const int*)d_in[1];    // int32 per harness contract
    const int*   rel    = (const int*)d_in[2];    // int32 per harness contract
    const float* weight = (const float*)d_in[4];
    const float* alpha  = (const float*)d_in[5];
    const float* bias   = (const float*)d_in[6];
    float*       out    = (float*)d_out;

    const int N = in_sizes[0] / 128;
    const int E = in_sizes[2];
    float* support = (float*)d_ws;   // N*128 floats = 51.2 MB

    // 1) out = broadcast(bias)
    long long total4 = (long long)N * 32;
    init_out_kernel<<<(int)((total4 + 255) / 256), 256, 0, stream>>>(out, bias, total4);

    // 2) support = input @ weight
    gemm_kernel<<<(N + 127) / 128, 256, 0, stream>>>(input, weight, support, N);

    // 3) scatter both directions with atomics
    long long tthreads = 2LL * E * 32;
    scatter_kernel<<<(int)((tthreads + 255) / 256), 256, 0, stream>>>(
        support, ei, rel, alpha, out, E);
}

// Round 3
// 683.770 us; speedup vs baseline: 7.9101x; 7.9101x over previous
//
#include <hip/hip_runtime.h>
#include <hip/hip_bf16.h>

// ---------------------------------------------------------------------------
// support[N,128] = A[N,128] @ W[128,128], fp32 vector ALU, 128-row tiles,
// 8x8 register blocking per thread, W/A K-chunks staged in LDS.
// ---------------------------------------------------------------------------
__global__ __launch_bounds__(256) void gemm_kernel(const float* __restrict__ A,
                                                   const float* __restrict__ W,
                                                   float* __restrict__ S,
                                                   int N) {
    __shared__ float sIn[128][33];   // +1 pad: conflict-free column reads
    __shared__ float sW[32][128];

    const int tid = threadIdx.x;
    const int tx = tid & 15;
    const int ty = tid >> 4;
    const int row0 = blockIdx.x * 128;

    float acc[8][8];
#pragma unroll
    for (int i = 0; i < 8; ++i)
#pragma unroll
        for (int j = 0; j < 8; ++j) acc[i][j] = 0.f;

    for (int kc = 0; kc < 128; kc += 32) {
#pragma unroll
        for (int p = 0; p < 4; ++p) {
            int r = p * 32 + (tid >> 3);
            int q = tid & 7;
            int grow = row0 + r;
            float4 v = make_float4(0.f, 0.f, 0.f, 0.f);
            if (grow < N) v = *(const float4*)&A[(size_t)grow * 128 + kc + q * 4];
            sIn[r][q * 4 + 0] = v.x;
            sIn[r][q * 4 + 1] = v.y;
            sIn[r][q * 4 + 2] = v.z;
            sIn[r][q * 4 + 3] = v.w;
        }
#pragma unroll
        for (int p = 0; p < 4; ++p) {
            int kr = p * 8 + (tid >> 5);
            int c4 = tid & 31;
            float4 v = *(const float4*)&W[(size_t)(kc + kr) * 128 + c4 * 4];
            *(float4*)&sW[kr][c4 * 4] = v;
        }
        __syncthreads();

#pragma unroll
        for (int k = 0; k < 32; ++k) {
            float a[8];
#pragma unroll
            for (int i = 0; i < 8; ++i) a[i] = sIn[ty * 8 + i][k];
            float4 w0 = *(float4*)&sW[k][tx * 4];
            float4 w1 = *(float4*)&sW[k][64 + tx * 4];
#pragma unroll
            for (int i = 0; i < 8; ++i) {
                acc[i][0] += a[i] * w0.x;
                acc[i][1] += a[i] * w0.y;
                acc[i][2] += a[i] * w0.z;
                acc[i][3] += a[i] * w0.w;
                acc[i][4] += a[i] * w1.x;
                acc[i][5] += a[i] * w1.y;
                acc[i][6] += a[i] * w1.z;
                acc[i][7] += a[i] * w1.w;
            }
        }
        __syncthreads();
    }

#pragma unroll
    for (int i = 0; i < 8; ++i) {
        int grow = row0 + ty * 8 + i;
        if (grow < N) {
            float4 v0 = make_float4(acc[i][0], acc[i][1], acc[i][2], acc[i][3]);
            float4 v1 = make_float4(acc[i][4], acc[i][5], acc[i][6], acc[i][7]);
            *(float4*)&S[(size_t)grow * 128 + tx * 4] = v0;
            *(float4*)&S[(size_t)grow * 128 + 64 + tx * 4] = v1;
        }
    }
}

// ---------------------------------------------------------------------------
// CSR build: zero -> count -> scan(3 kernels) -> fill
// Message m in [0,2E): dst = ei[m]; src = ei[m<E ? m+E : m-E]; e = m mod E.
// ---------------------------------------------------------------------------
__global__ __launch_bounds__(256) void zero_u32_kernel(unsigned* __restrict__ p, int n) {
    int i = blockIdx.x * 256 + threadIdx.x;
    if (i < n) p[i] = 0u;
}

__global__ __launch_bounds__(256) void count_kernel(const int* __restrict__ ei,
                                                    unsigned* __restrict__ deg,
                                                    int E) {
    long long m = (long long)blockIdx.x * 256 + threadIdx.x;
    if (m >= 2LL * E) return;
    atomicAdd(&deg[ei[m]], 1u);
}

#define SCAN_TPB 256
#define SCAN_ELEMS 1024  // elements per scan block (4 per thread)

__global__ __launch_bounds__(SCAN_TPB) void scan_block_kernel(const unsigned* __restrict__ deg,
                                                              unsigned* __restrict__ off,
                                                              unsigned* __restrict__ partials,
                                                              int N) {
    __shared__ unsigned s[SCAN_TPB];
    const int t = threadIdx.x;
    const int base = blockIdx.x * SCAN_ELEMS + t * 4;
    unsigned v[4];
#pragma unroll
    for (int i = 0; i < 4; ++i) v[i] = (base + i < N) ? deg[base + i] : 0u;
    unsigned run = 0;
#pragma unroll
    for (int i = 0; i < 4; ++i) { unsigned tmp = v[i]; v[i] = run; run += tmp; }
    s[t] = run;
    __syncthreads();
    for (int d = 1; d < SCAN_TPB; d <<= 1) {
        unsigned x = (t >= d) ? s[t - d] : 0u;
        __syncthreads();
        s[t] += x;
        __syncthreads();
    }
    unsigned texcl = (t == 0) ? 0u : s[t - 1];
#pragma unroll
    for (int i = 0; i < 4; ++i)
        if (base + i < N) off[base + i] = v[i] + texcl;
    if (t == SCAN_TPB - 1) partials[blockIdx.x] = s[SCAN_TPB - 1];
}

__global__ __launch_bounds__(SCAN_TPB) void scan_partials_kernel(unsigned* __restrict__ partials,
                                                                 int nb) {
    __shared__ unsigned s[SCAN_TPB];
    const int t = threadIdx.x;
    unsigned carry = 0;
    for (int base = 0; base < nb; base += SCAN_TPB) {
        int i = base + t;
        s[t] = (i < nb) ? partials[i] : 0u;
        __syncthreads();
        for (int d = 1; d < SCAN_TPB; d <<= 1) {
            unsigned x = (t >= d) ? s[t - d] : 0u;
            __syncthreads();
            s[t] += x;
            __syncthreads();
        }
        unsigned excl = carry + ((t == 0) ? 0u : s[t - 1]);
        if (i < nb) partials[i] = excl;
        carry += s[SCAN_TPB - 1];
        __syncthreads();
    }
}

__global__ __launch_bounds__(256) void add_offsets_kernel(unsigned* __restrict__ off,
                                                          unsigned* __restrict__ cursor,
                                                          const unsigned* __restrict__ partials,
                                                          int N) {
    int i = blockIdx.x * 256 + threadIdx.x;
    if (i >= N) return;
    unsigned o = off[i] + partials[i / SCAN_ELEMS];
    off[i] = o;
    cursor[i] = o;
}

__global__ __launch_bounds__(256) void fill_kernel(const int* __restrict__ ei,
                                                   const int* __restrict__ rel,
                                                   unsigned* __restrict__ cursor,
                                                   unsigned* __restrict__ rec,
                                                   int E) {
    long long m = (long long)blockIdx.x * 256 + threadIdx.x;
    if (m >= 2LL * E) return;
    int dst = ei[m];
    long long ms = (m < E) ? m + E : m - E;
    int src = ei[ms];
    int e = (int)((m < E) ? m : m - E);
    unsigned rr = (unsigned)rel[e];
    unsigned pos = atomicAdd(&cursor[dst], 1u);
    rec[pos] = (unsigned)src | (rr << 24);   // N < 2^24, rel < 256
}

// ---------------------------------------------------------------------------
// Gather: one 32-lane half-wave per node; lane owns float4 (128 = 32*4).
// out[node] = bias + sum_j alpha[rel_j] * support[src_j]   (single writer)
// ---------------------------------------------------------------------------
__global__ __launch_bounds__(256) void gather_kernel(const float* __restrict__ support,
                                                     const unsigned* __restrict__ rec,
                                                     const unsigned* __restrict__ off,
                                                     const unsigned* __restrict__ deg,
                                                     const float* __restrict__ alpha,
                                                     const float* __restrict__ bias,
                                                     float* __restrict__ out,
                                                     int N) {
    int hw = (int)(((long long)blockIdx.x * 256 + threadIdx.x) >> 5);
    int lane = threadIdx.x & 31;
    if (hw >= N) return;

    const unsigned start = off[hw];
    const unsigned d = deg[hw];
    float4 acc = make_float4(0.f, 0.f, 0.f, 0.f);

    unsigned j = 0;
    for (; j + 2 <= d; j += 2) {   // unroll-2 for load-latency overlap
        unsigned r0 = rec[start + j];
        unsigned r1 = rec[start + j + 1];
        const float4 v0 = *(const float4*)&support[(size_t)(r0 & 0xFFFFFFu) * 128 + lane * 4];
        const float4 v1 = *(const float4*)&support[(size_t)(r1 & 0xFFFFFFu) * 128 + lane * 4];
        unsigned rr0 = r0 >> 24, rr1 = r1 >> 24;
        float a0 = (rr0 == 0u) ? 0.f : alpha[rr0];
        float a1 = (rr1 == 0u) ? 0.f : alpha[rr1];
        acc.x += a0 * v0.x; acc.y += a0 * v0.y; acc.z += a0 * v0.z; acc.w += a0 * v0.w;
        acc.x += a1 * v1.x; acc.y += a1 * v1.y; acc.z += a1 * v1.z; acc.w += a1 * v1.w;
    }
    if (j < d) {
        unsigned r0 = rec[start + j];
        const float4 v0 = *(const float4*)&support[(size_t)(r0 & 0xFFFFFFu) * 128 + lane * 4];
        unsigned rr0 = r0 >> 24;
        float a0 = (rr0 == 0u) ? 0.f : alpha[rr0];
        acc.x += a0 * v0.x; acc.y += a0 * v0.y; acc.z += a0 * v0.z; acc.w += a0 * v0.w;
    }

    const float4 b = *(const float4*)&bias[lane * 4];
    float4 o = make_float4(acc.x + b.x, acc.y + b.y, acc.z + b.z, acc.w + b.w);
    *(float4*)&out[(size_t)hw * 128 + lane * 4] = o;
}

// ---------------------------------------------------------------------------
// Fallback (ws too small): bias-init + fp32 atomic scatter (round-2 version)
// ---------------------------------------------------------------------------
__global__ __launch_bounds__(256) void init_out_kernel(float* __restrict__ out,
                                                       const float* __restrict__ bias,
                                                       long long total4) {
    long long i = (long long)blockIdx.x * blockDim.x + threadIdx.x;
    if (i >= total4) return;
    float4 b = ((const float4*)bias)[(int)(i & 31)];
    ((float4*)out)[i] = b;
}

__global__ __launch_bounds__(256) void scatter_kernel(const float* __restrict__ support,
                                                      const int* __restrict__ ei,
                                                      const int* __restrict__ rel,
                                                      const float* __restrict__ alpha,
                                                      float* __restrict__ out,
                                                      int E) {
    long long tid = (long long)blockIdx.x * blockDim.x + threadIdx.x;
    long long mid = tid >> 5;
    if (mid >= 2LL * E) return;
    int lane4 = (int)(tid & 31);
    int dst = ei[mid];
    long long ms = (mid < E) ? mid + E : mid - E;
    int src = ei[ms];
    int e = (int)((mid < E) ? mid : mid - E);
    int rr = rel[e];
    float alp = (rr == 0) ? 0.f : alpha[rr];
    if (alp == 0.f) return;
    const float4 v = *(const float4*)&support[(size_t)src * 128 + lane4 * 4];
    float* o = &out[(size_t)dst * 128 + lane4 * 4];
    atomicAdd(o + 0, alp * v.x);
    atomicAdd(o + 1, alp * v.y);
    atomicAdd(o + 2, alp * v.z);
    atomicAdd(o + 3, alp * v.w);
}

extern "C" void kernel_launch(void* const* d_in, const int* in_sizes, int n_in,
                              void* d_out, int out_size, void* d_ws, size_t ws_size,
                              hipStream_t stream) {
    const float* input  = (const float*)d_in[0];
    const int*   ei     = (const int*)d_in[1];    // int32 per harness contract
    const int*   rel    = (const int*)d_in[2];
    const float* weight = (const float*)d_in[4];
    const float* alpha  = (const float*)d_in[5];
    const float* bias   = (const float*)d_in[6];
    float*       out    = (float*)d_out;

    const int N = in_sizes[0] / 128;
    const int E = in_sizes[2];
    const long long M = 2LL * E;                  // directed messages

    // workspace layout (all 16B-aligned)
    char* ws = (char*)d_ws;
    const size_t supB = (size_t)N * 128 * 4;
    const size_t degB = (size_t)N * 4;
    const int    nb   = (N + SCAN_ELEMS - 1) / SCAN_ELEMS;
    const size_t parB = 4096;                     // up to 1024 partials
    const size_t recB = (size_t)M * 4;

    float*    support  = (float*)ws;
    unsigned* deg      = (unsigned*)(ws + supB);
    unsigned* off      = (unsigned*)(ws + supB + degB);
    unsigned* cursor   = (unsigned*)(ws + supB + 2 * degB);
    unsigned* partials = (unsigned*)(ws + supB + 3 * degB);
    unsigned* rec      = (unsigned*)(ws + supB + 3 * degB + parB);
    const size_t need  = supB + 3 * degB + parB + recB;

    // 1) support = input @ weight
    gemm_kernel<<<(N + 127) / 128, 256, 0, stream>>>(input, weight, support, N);

    const int mBlocks = (int)((M + 255) / 256);

    if (ws_size >= need && N < (1 << 24) && nb <= 1024) {
        // 2) CSR build over destinations
        zero_u32_kernel<<<(N + 255) / 256, 256, 0, stream>>>(deg, N);
        count_kernel<<<mBlocks, 256, 0, stream>>>(ei, deg, E);
        scan_block_kernel<<<nb, SCAN_TPB, 0, stream>>>(deg, off, partials, N);
        scan_partials_kernel<<<1, SCAN_TPB, 0, stream>>>(partials, nb);
        add_offsets_kernel<<<(N + 255) / 256, 256, 0, stream>>>(off, cursor, partials, N);
        fill_kernel<<<mBlocks, 256, 0, stream>>>(ei, rel, cursor, rec, E);
        // 3) gather-reduce, bias folded, single writer per node
        long long gthreads = (long long)N * 32;
        gather_kernel<<<(int)((gthreads + 255) / 256), 256, 0, stream>>>(
            support, rec, off, deg, alpha, bias, out, N);
    } else {
        // fallback: atomic scatter
        long long total4 = (long long)N * 32;
        init_out_kernel<<<(int)((total4 + 255) / 256), 256, 0, stream>>>(out, bias, total4);
        long long tthreads = M * 32;
        scatter_kernel<<<(int)((tthreads + 255) / 256), 256, 0, stream>>>(
            support, ei, rel, alpha, out, E);
    }
}